// Round 17
// baseline (471.693 us; speedup 1.0000x reference)
//
#include <hip/hip_runtime.h>
#include <hip/hip_bf16.h>

// Problem constants
#define Bn 16
#define Sn 16
#define Ln 64
#define En 512
#define Hn 512
#define Nn 512   // B*2*S packed batch
#define G4 2048  // 4*H

typedef __bf16 bf16x8 __attribute__((ext_vector_type(8)));
typedef float f32x4 __attribute__((ext_vector_type(4)));
typedef unsigned short u16x8 __attribute__((ext_vector_type(8)));
typedef unsigned short u16x4 __attribute__((ext_vector_type(4)));

__device__ __forceinline__ unsigned short f2bf(float f) {
    union { float f; unsigned u; } v; v.f = f;
    unsigned r = v.u + 0x7FFFu + ((v.u >> 16) & 1u);   // RNE
    return (unsigned short)(r >> 16);
}
__device__ __forceinline__ float bf2f(unsigned short u) {
    union { unsigned u; float f; } v; v.u = ((unsigned)u) << 16;
    return v.f;
}
__device__ __forceinline__ float sigmf(float x) {
    return 1.0f / (1.0f + __expf(-x));
}
__device__ __forceinline__ float tanh_fast(float x) {
    x = fminf(fmaxf(x, -15.0f), 15.0f);
    float e = __expf(2.0f * x);
    return (e - 1.0f) / (e + 1.0f);
}

// ---------------------------------------------------------------------------
// ws layout (bytes)
// Wihb row order is PACKED-COL order: row p = ut*64 + u15*4 + gate
//   (p <-> gcol = gate*512 + ut*16 + u15), chunk^(p&7) swizzle.
// ---------------------------------------------------------------------------
#define WS_WIHB  0            // Wih bf16 [p 2048][k 512]                    2MB
#define WS_WHH   2097152      // Whh image [ut 32][grow 64][k 512], ch^(grow&7) 2MB
#define WS_BSUM  4194304      // fp32 2048
#define WS_HA    4202496      // h bf16 [n 512][k 512], chunk^(n&7) swizzle   512KB
#define WS_HB    4726784      // 512KB
#define WS_C     5251072      // fp32 [n][u] 1MB
#define WS_FEAT  6299648      // 128KB
#define WS_Z1    6430720      // 16KB
#define WS_XBF   6447104      // x bf16 [m 32768][k 512], chunk^(m&7)  32MB
#define WS_XG    40001536     // Xg bf16 [m 32768][p 2048] (p = ut*64+u15*4+gate) 134MB

// prep_all regions
#define R_WI   131072
#define R_WH   262144
#define R_BS   264192
#define R_HZ   296960
#define R_CZ   362496
#define R_XP   2459648        // + 2097152 prep_x chunks
#define PREP_BLOCKS (R_XP / 256)   // 9608

__global__ __launch_bounds__(256) void prep_all(
    const float* __restrict__ Wih_f, const float* __restrict__ Whh_f,
    const float* __restrict__ bih, const float* __restrict__ bhh,
    const float* __restrict__ xf, const float* __restrict__ xa,
    unsigned short* __restrict__ Wihb, unsigned short* __restrict__ WhhImg,
    float* __restrict__ bsum, unsigned short* __restrict__ hA,
    float* __restrict__ c0, unsigned short* __restrict__ Xbf) {
    int i = blockIdx.x * 256 + threadIdx.x;
    if (i < R_WI) {
        int gcol = i >> 6, ch = i & 63;
        int gate = gcol >> 9, unit = gcol & 511;
        int p = (unit >> 4) * 64 + (unit & 15) * 4 + gate;   // packed-col row
        const float* s = Wih_f + (size_t)gcol * 512 + ch * 8;
        u16x8 w;
#pragma unroll
        for (int j = 0; j < 8; ++j) w[j] = f2bf(s[j]);
        *(u16x8*)(Wihb + (size_t)p * 512 + (ch ^ (p & 7)) * 8) = w;
    } else if (i < R_WH) {
        int j = i - R_WI;
        int g4row = j >> 6, ch = j & 63;
        int gate = g4row >> 9, unit = g4row & 511;
        int ut = unit >> 4, grow = gate * 16 + (unit & 15);
        const float* s = Whh_f + (size_t)g4row * 512 + ch * 8;
        u16x8 w;
#pragma unroll
        for (int k = 0; k < 8; ++k) w[k] = f2bf(s[k]);
        *(u16x8*)(WhhImg + ut * 32768 + grow * 512 + (ch ^ (grow & 7)) * 8) = w;
    } else if (i < R_BS) {
        int j = i - R_WH;
        bsum[j] = bih[j] + bhh[j];
    } else if (i < R_HZ) {
        int j = i - R_BS;
        u16x8 z = {0, 0, 0, 0, 0, 0, 0, 0};
        *(u16x8*)(hA + j * 8) = z;
    } else if (i < R_CZ) {
        int j = i - R_HZ;
        f32x4 z = {0.f, 0.f, 0.f, 0.f};
        *(f32x4*)(c0 + j * 4) = z;
    } else if (i < R_XP) {
        int j = i - R_CZ;
        int m = j >> 6, k8 = j & 63;
        int t = m >> 9, n = m & 511;
        int bb = n >> 5, rr = n & 31;
        const float* src = ((rr < Sn)
            ? xf + ((size_t)(bb * Sn + rr) * Ln + t) * En
            : xa + ((size_t)(bb * Sn + (rr - Sn)) * Ln + t) * En) + k8 * 8;
        float4 v0 = *(const float4*)src;
        float4 v1 = *(const float4*)(src + 4);
        u16x8 w;
        w[0] = f2bf(v0.x); w[1] = f2bf(v0.y); w[2] = f2bf(v0.z); w[3] = f2bf(v0.w);
        w[4] = f2bf(v1.x); w[5] = f2bf(v1.y); w[6] = f2bf(v1.z); w[7] = f2bf(v1.w);
        *(u16x8*)(Xbf + (size_t)m * 512 + (k8 ^ (m & 7)) * 8) = w;
    }
}

// ---------------------------------------------------------------------------
// Xg = Xbf @ Wih^T : M=32768, N=2048 (packed cols), K=512. 128x128 tile,
// BK=64, XCD-chunked block map, linear LDS staging, swizzled images.
// SINGLE-buffered LDS (32KB -> 5 blocks/CU) + register prefetch; 2 barriers.
// Epilogue: contiguous packed-col store.
// ---------------------------------------------------------------------------
__global__ __launch_bounds__(256) void xg_gemm(
    const unsigned short* __restrict__ Xbf,
    const unsigned short* __restrict__ Wihb,
    unsigned short* __restrict__ Xg) {
    __shared__ __align__(16) unsigned short As[8192];  // [128 rows][64 k] 16KB
    __shared__ __align__(16) unsigned short Bs[8192];
    const int tid = threadIdx.x;
    const int p = blockIdx.x;
    const int L = (p & 7) * 512 + (p >> 3);   // bijective XCD-chunked map
    const int bx = L >> 4, by = L & 15;
    const size_t m0 = (size_t)bx * 128;
    const int n0 = by * 128;
    const int wv = tid >> 6, lane = tid & 63;
    const int l15 = lane & 15, sel = lane >> 4;
    const int wm = wv >> 1, wn = wv & 1;

    // staging: thread tid <-> LDS byte tid*16 (+r*4096); linear, conflict-free
    const int srow = tid >> 3;        // + r*32
    const int sseg = tid & 7;         // *8 u16
    const unsigned short* asrc = Xbf + (m0 + srow) * 512 + sseg * 8;
    const unsigned short* bsrc = Wihb + (size_t)(n0 + srow) * 512 + sseg * 8;

    f32x4 acc[4][4];
#pragma unroll
    for (int i = 0; i < 4; ++i)
#pragma unroll
        for (int j = 0; j < 4; ++j) acc[i][j] = (f32x4){0.f, 0.f, 0.f, 0.f};

    u16x8 ar[4], br[4];
#pragma unroll
    for (int r = 0; r < 4; ++r) {
        ar[r] = *(const u16x8*)(asrc + (size_t)r * 32 * 512);
        br[r] = *(const u16x8*)(bsrc + (size_t)r * 32 * 512);
    }

#pragma unroll 1
    for (int it = 0; it < 8; ++it) {
        // write current tile (linear, conflict-free)
#pragma unroll
        for (int r = 0; r < 4; ++r) {
            *(u16x8*)((char*)As + r * 4096 + tid * 16) = ar[r];
            *(u16x8*)((char*)Bs + r * 4096 + tid * 16) = br[r];
        }
        // prefetch next tile into regs (completes during MFMA phase)
        if (it < 7) {
#pragma unroll
            for (int r = 0; r < 4; ++r) {
                ar[r] = *(const u16x8*)(asrc + (size_t)r * 32 * 512 + (it + 1) * 64);
                br[r] = *(const u16x8*)(bsrc + (size_t)r * 32 * 512 + (it + 1) * 64);
            }
        }
        __syncthreads();   // writes visible
#pragma unroll
        for (int ks = 0; ks < 2; ++ks) {
            bf16x8 a[4], b[4];
#pragma unroll
            for (int i = 0; i < 4; ++i) {
                const int arow = wm * 64 + i * 16 + l15;
                a[i] = *(const bf16x8*)(As + arow * 64 + (((ks * 4 + sel) ^ (arow & 7)) * 8));
                const int brow = wn * 64 + i * 16 + l15;
                b[i] = *(const bf16x8*)(Bs + brow * 64 + (((ks * 4 + sel) ^ (brow & 7)) * 8));
            }
#pragma unroll
            for (int i = 0; i < 4; ++i)
#pragma unroll
                for (int j = 0; j < 4; ++j)
                    acc[i][j] = __builtin_amdgcn_mfma_f32_16x16x32_bf16(a[i], b[j], acc[i][j], 0, 0, 0);
        }
        __syncthreads();   // reads done before next iter overwrites
    }
    // epilogue: contiguous packed-col store
#pragma unroll
    for (int i = 0; i < 4; ++i)
#pragma unroll
        for (int j = 0; j < 4; ++j) {
            const int col = n0 + wn * 64 + j * 16 + l15;
#pragma unroll
            for (int q = 0; q < 4; ++q) {
                const size_t m = m0 + wm * 64 + i * 16 + sel * 4 + q;
                Xg[m * 2048 + col] = f2bf(acc[i][j][q]);
            }
        }
}

// ---------------------------------------------------------------------------
// One LSTM step: gates = Xg[t] + h @ Whh^T; cell; h stored swizzled.
// Grid 256 (nt8 FAST x ut32), 512 thr = 8 waves (wm2 x wn4).
// BK=128 x 4 iters, double-buffered (64KB LDS): halves barrier count vs BK=64
// (6 barriers/step vs 10). Reader chunk formula extends: logical chunk
// g = it*16+ch, phys = g^(row&7) = it*16 + (ch^(row&7)) since it*16 has
// zero low bits. nt = bid&7 => single owning XCD per h/c region.
// ---------------------------------------------------------------------------
__global__ __launch_bounds__(512) void lstm_step(
    const unsigned short* __restrict__ WhhImg,
    const unsigned short* __restrict__ Xg, const float* __restrict__ bsum,
    const unsigned short* __restrict__ h_in, unsigned short* __restrict__ h_out,
    float* __restrict__ c, int t) {
    __shared__ __align__(16) char smem[65536];
    // H buffers @0,16K ; W buffers @32K,48K ; dump overlays 0..16K after loop
    float* dump = (float*)smem;          // [gate 4][row 64][cj 16]

    const int tid = threadIdx.x, bid = blockIdx.x;
    const int nt = bid & 7, ut = bid >> 3;
    const int n0 = nt * 64, u0 = ut * 16;
    const int wv = tid >> 6, lane = tid & 63;
    const int l15 = lane & 15, sel = lane >> 4;
    const int wm = wv >> 2, wn = wv & 3;         // wave tile: rows wm*32, gate wn
    const int srow = tid >> 3, sseg = tid & 7;
    const int wofs = srow * 256 + sseg * 32;     // 32B per thread per tile

    const unsigned short* hsrc = h_in + (size_t)(n0 + srow) * 512 + sseg * 16;
    const unsigned short* wsrc = WhhImg + ut * 32768 + srow * 512 + sseg * 16;

    f32x4 acc0 = (f32x4){0.f, 0.f, 0.f, 0.f};
    f32x4 acc1 = (f32x4){0.f, 0.f, 0.f, 0.f};

    u16x8 hv0 = *(const u16x8*)hsrc;
    u16x8 hv1 = *(const u16x8*)(hsrc + 8);
    u16x8 wr0 = *(const u16x8*)wsrc;
    u16x8 wr1 = *(const u16x8*)(wsrc + 8);

#pragma unroll
    for (int it = 0; it < 4; ++it) {
        char* H = smem + (it & 1) * 16384;
        char* W = smem + 32768 + (it & 1) * 16384;
        *(u16x8*)(H + wofs) = hv0;
        *(u16x8*)(H + wofs + 16) = hv1;
        *(u16x8*)(W + wofs) = wr0;
        *(u16x8*)(W + wofs + 16) = wr1;
        if (it < 3) {
            hv0 = *(const u16x8*)(hsrc + (it + 1) * 128);
            hv1 = *(const u16x8*)(hsrc + (it + 1) * 128 + 8);
            wr0 = *(const u16x8*)(wsrc + (it + 1) * 128);
            wr1 = *(const u16x8*)(wsrc + (it + 1) * 128 + 8);
        }
        __syncthreads();
#pragma unroll
        for (int ks = 0; ks < 4; ++ks) {
            const int ar0 = wm * 32 + l15, ar1 = ar0 + 16;
            const int br = wn * 16 + l15;
            const int ch = ks * 4 + sel;
            bf16x8 a0 = *(const bf16x8*)(H + ar0 * 256 + ((ch ^ (ar0 & 7)) * 16));
            bf16x8 a1 = *(const bf16x8*)(H + ar1 * 256 + ((ch ^ (ar1 & 7)) * 16));
            bf16x8 b  = *(const bf16x8*)(W + br * 256 + ((ch ^ (br & 7)) * 16));
            acc0 = __builtin_amdgcn_mfma_f32_16x16x32_bf16(a0, b, acc0, 0, 0, 0);
            acc1 = __builtin_amdgcn_mfma_f32_16x16x32_bf16(a1, b, acc1, 0, 0, 0);
        }
    }
    __syncthreads();   // all reads of LDS buffers done before dump overlays them

    // gate dump: wave (wm,wn) holds gate wn rows wm*32..+31
#pragma unroll
    for (int f = 0; f < 2; ++f)
#pragma unroll
        for (int q = 0; q < 4; ++q) {
            const int r = wm * 32 + f * 16 + sel * 4 + q;
            dump[wn * 1024 + r * 16 + l15] = (f ? acc1 : acc0)[q];
        }
    __syncthreads();

    // cell: 2 cells/thread; Xg packed u16x4 read
    const int crow = tid >> 4, cj = tid & 15;
    const float bI = bsum[u0 + cj];
    const float bF = bsum[512 + u0 + cj];
    const float bG = bsum[1024 + u0 + cj];
    const float bO = bsum[1536 + u0 + cj];
#pragma unroll
    for (int half = 0; half < 2; ++half) {
        const int r = crow + half * 32;
        const int n = n0 + r;
        const u16x4 xv = *(const u16x4*)(Xg + ((size_t)t * 512 + n) * 2048 + ut * 64 + cj * 4);
        const float gi = dump[0 * 1024 + r * 16 + cj] + bf2f(xv[0]) + bI;
        const float gf = dump[1 * 1024 + r * 16 + cj] + bf2f(xv[1]) + bF;
        const float gg = dump[2 * 1024 + r * 16 + cj] + bf2f(xv[2]) + bG;
        const float go = dump[3 * 1024 + r * 16 + cj] + bf2f(xv[3]) + bO;
        const size_t ci = (size_t)n * 512 + u0 + cj;
        const float I = sigmf(gi), F = sigmf(gf);
        const float G = tanh_fast(gg), O = sigmf(go);
        const float cn = F * c[ci] + I * G;
        c[ci] = cn;
        const int chunk = (ut * 2 + (cj >> 3)) ^ (n & 7);
        h_out[(size_t)n * 512 + chunk * 8 + (cj & 7)] = f2bf(O * tanh_fast(cn));
    }
}

// ---------------------------------------------------------------------------
// Head: pool (de-swizzle), fc1, fc2.
// ---------------------------------------------------------------------------
__global__ __launch_bounds__(256) void pool_kernel(
    const unsigned short* __restrict__ hfin, float* __restrict__ feat) {
    const int blk = blockIdx.x;
    const int b = blk >> 1, side = blk & 1;
    const int tid = threadIdx.x;
    for (int u = tid; u < Hn; u += 256) {
        float s = 0.0f, m = -1e30f;
#pragma unroll
        for (int ss = 0; ss < Sn; ++ss) {
            const int n = b * 32 + side * 16 + ss;
            const int chunk = (u >> 3) ^ (n & 7);
            float v = bf2f(hfin[(size_t)n * 512 + chunk * 8 + (u & 7)]);
            s += v;
            m = fmaxf(m, v);
        }
        feat[b * 2048 + side * 1024 + u] = s * (1.0f / 16.0f);
        feat[b * 2048 + side * 1024 + 512 + u] = m;
    }
}

__global__ __launch_bounds__(256) void fc1_kernel(
    const float* __restrict__ feat, const float* __restrict__ fc1w,
    const float* __restrict__ fc1b, float* __restrict__ z1) {
    __shared__ float fs[2048];
    __shared__ float red[256];
    const int b = blockIdx.x >> 4, oc = blockIdx.x & 15;
    const int tid = threadIdx.x;
    for (int k = tid; k < 2048; k += 256) fs[k] = feat[b * 2048 + k];
    __syncthreads();
    const int o = oc * 16 + (tid & 15);
    const int ks = (tid >> 4) * 128;
    const float4* w4 = (const float4*)(fc1w + (size_t)o * 2048 + ks);
    const float* fr = fs + ks;
    float p = 0.0f;
#pragma unroll 8
    for (int k = 0; k < 32; ++k) {
        float4 w = w4[k];
        p += fr[k * 4] * w.x + fr[k * 4 + 1] * w.y +
             fr[k * 4 + 2] * w.z + fr[k * 4 + 3] * w.w;
    }
    red[(tid & 15) * 16 + (tid >> 4)] = p;
    __syncthreads();
    if (tid < 16) {
        float z = fc1b[oc * 16 + tid];
#pragma unroll
        for (int j = 0; j < 16; ++j) z += red[tid * 16 + j];
        z1[b * 256 + oc * 16 + tid] = z;
    }
}

__global__ __launch_bounds__(256) void fc2_kernel(
    const float* __restrict__ z1, const float* __restrict__ fc2w,
    const float* __restrict__ fc2b, float* __restrict__ out) {
    __shared__ float sh[256];
    const int b = blockIdx.x, tid = threadIdx.x;
    sh[tid] = z1[b * 256 + tid] * fc2w[tid];
    __syncthreads();
    for (int s = 128; s > 0; s >>= 1) {
        if (tid < s) sh[tid] += sh[tid + s];
        __syncthreads();
    }
    if (tid == 0) out[b] = sigmf(sh[0] + fc2b[0]);
}

// ---------------------------------------------------------------------------
extern "C" void kernel_launch(void* const* d_in, const int* in_sizes, int n_in,
                              void* d_out, int out_size, void* d_ws, size_t ws_size,
                              hipStream_t stream) {
    const float* xf    = (const float*)d_in[0];
    const float* xa    = (const float*)d_in[1];
    const float* Wih_f = (const float*)d_in[2];
    const float* Whh_f = (const float*)d_in[3];
    const float* bih   = (const float*)d_in[4];
    const float* bhh   = (const float*)d_in[5];
    const float* fc1w  = (const float*)d_in[6];
    const float* fc1b  = (const float*)d_in[7];
    const float* fc2w  = (const float*)d_in[8];
    const float* fc2b  = (const float*)d_in[9];
    float* out = (float*)d_out;

    char* ws = (char*)d_ws;
    unsigned short* Wihb   = (unsigned short*)(ws + WS_WIHB);
    unsigned short* WhhImg = (unsigned short*)(ws + WS_WHH);
    float*          bsum   = (float*)(ws + WS_BSUM);
    unsigned short* hA     = (unsigned short*)(ws + WS_HA);
    unsigned short* hB     = (unsigned short*)(ws + WS_HB);
    float*          cbuf   = (float*)(ws + WS_C);
    float*          feat   = (float*)(ws + WS_FEAT);
    float*          z1     = (float*)(ws + WS_Z1);
    unsigned short* Xbf    = (unsigned short*)(ws + WS_XBF);
    unsigned short* Xg     = (unsigned short*)(ws + WS_XG);

    prep_all<<<dim3(PREP_BLOCKS), dim3(256), 0, stream>>>(
        Wih_f, Whh_f, bih, bhh, xf, xa, Wihb, WhhImg, bsum, hA, cbuf, Xbf);

    xg_gemm<<<dim3(4096), dim3(256), 0, stream>>>(Xbf, Wihb, Xg);

    for (int t = 0; t < Ln; ++t) {
        const unsigned short* hin = (t & 1) ? hB : hA;
        unsigned short* hout      = (t & 1) ? hA : hB;
        lstm_step<<<dim3(256), dim3(512), 0, stream>>>(
            WhhImg, Xg, bsum, hin, hout, cbuf, t);
    }
    // t=63 wrote hA
    pool_kernel<<<dim3(32), dim3(256), 0, stream>>>(hA, feat);
    fc1_kernel<<<dim3(256), dim3(256), 0, stream>>>(feat, fc1w, fc1b, z1);
    fc2_kernel<<<dim3(16), dim3(256), 0, stream>>>(z1, fc2w, fc2b, out);
}

// Round 18
// 416.589 us; speedup vs baseline: 1.1323x; 1.1323x over previous
//
#include <hip/hip_runtime.h>
#include <hip/hip_bf16.h>

// Problem constants
#define Bn 16
#define Sn 16
#define Ln 64
#define En 512
#define Hn 512
#define Nn 512   // B*2*S packed batch
#define G4 2048  // 4*H

typedef __bf16 bf16x8 __attribute__((ext_vector_type(8)));
typedef float f32x4 __attribute__((ext_vector_type(4)));
typedef unsigned short u16x8 __attribute__((ext_vector_type(8)));
typedef unsigned short u16x4 __attribute__((ext_vector_type(4)));

__device__ __forceinline__ unsigned short f2bf(float f) {
    union { float f; unsigned u; } v; v.f = f;
    unsigned r = v.u + 0x7FFFu + ((v.u >> 16) & 1u);   // RNE
    return (unsigned short)(r >> 16);
}
__device__ __forceinline__ float bf2f(unsigned short u) {
    union { unsigned u; float f; } v; v.u = ((unsigned)u) << 16;
    return v.f;
}
__device__ __forceinline__ float sigmf(float x) {
    return 1.0f / (1.0f + __expf(-x));
}
__device__ __forceinline__ float tanh_fast(float x) {
    x = fminf(fmaxf(x, -15.0f), 15.0f);
    float e = __expf(2.0f * x);
    return (e - 1.0f) / (e + 1.0f);
}

// ---------------------------------------------------------------------------
// ws layout (bytes)
// Wihb row order is PACKED-COL order: row p = ut*64 + u15*4 + gate
//   (p <-> gcol = gate*512 + ut*16 + u15), chunk^(p&7) swizzle.
// ---------------------------------------------------------------------------
#define WS_WIHB  0            // Wih bf16 [p 2048][k 512]                    2MB
#define WS_WHH   2097152      // Whh image [ut 32][grow 64][k 512], ch^(grow&7) 2MB
#define WS_BSUM  4194304      // fp32 2048
#define WS_HA    4202496      // h bf16 [n 512][k 512], chunk^(n&7) swizzle   512KB
#define WS_HB    4726784      // 512KB
#define WS_C     5251072      // fp32 [n][u] 1MB
#define WS_FEAT  6299648      // 128KB
#define WS_Z1    6430720      // 16KB
#define WS_XBF   6447104      // x bf16 [m 32768][k 512], chunk^(m&7)  32MB
#define WS_XG    40001536     // Xg bf16 [m 32768][p 2048] (p = ut*64+u15*4+gate) 134MB

// prep_all regions
#define R_WI   131072
#define R_WH   262144
#define R_BS   264192
#define R_HZ   296960
#define R_CZ   362496
#define R_XP   2459648        // + 2097152 prep_x chunks
#define PREP_BLOCKS (R_XP / 256)   // 9608

__global__ __launch_bounds__(256) void prep_all(
    const float* __restrict__ Wih_f, const float* __restrict__ Whh_f,
    const float* __restrict__ bih, const float* __restrict__ bhh,
    const float* __restrict__ xf, const float* __restrict__ xa,
    unsigned short* __restrict__ Wihb, unsigned short* __restrict__ WhhImg,
    float* __restrict__ bsum, unsigned short* __restrict__ hA,
    float* __restrict__ c0, unsigned short* __restrict__ Xbf) {
    int i = blockIdx.x * 256 + threadIdx.x;
    if (i < R_WI) {
        int gcol = i >> 6, ch = i & 63;
        int gate = gcol >> 9, unit = gcol & 511;
        int p = (unit >> 4) * 64 + (unit & 15) * 4 + gate;   // packed-col row
        const float* s = Wih_f + (size_t)gcol * 512 + ch * 8;
        u16x8 w;
#pragma unroll
        for (int j = 0; j < 8; ++j) w[j] = f2bf(s[j]);
        *(u16x8*)(Wihb + (size_t)p * 512 + (ch ^ (p & 7)) * 8) = w;
    } else if (i < R_WH) {
        int j = i - R_WI;
        int g4row = j >> 6, ch = j & 63;
        int gate = g4row >> 9, unit = g4row & 511;
        int ut = unit >> 4, grow = gate * 16 + (unit & 15);
        const float* s = Whh_f + (size_t)g4row * 512 + ch * 8;
        u16x8 w;
#pragma unroll
        for (int k = 0; k < 8; ++k) w[k] = f2bf(s[k]);
        *(u16x8*)(WhhImg + ut * 32768 + grow * 512 + (ch ^ (grow & 7)) * 8) = w;
    } else if (i < R_BS) {
        int j = i - R_WH;
        bsum[j] = bih[j] + bhh[j];
    } else if (i < R_HZ) {
        int j = i - R_BS;
        u16x8 z = {0, 0, 0, 0, 0, 0, 0, 0};
        *(u16x8*)(hA + j * 8) = z;
    } else if (i < R_CZ) {
        int j = i - R_HZ;
        f32x4 z = {0.f, 0.f, 0.f, 0.f};
        *(f32x4*)(c0 + j * 4) = z;
    } else if (i < R_XP) {
        int j = i - R_CZ;
        int m = j >> 6, k8 = j & 63;
        int t = m >> 9, n = m & 511;
        int bb = n >> 5, rr = n & 31;
        const float* src = ((rr < Sn)
            ? xf + ((size_t)(bb * Sn + rr) * Ln + t) * En
            : xa + ((size_t)(bb * Sn + (rr - Sn)) * Ln + t) * En) + k8 * 8;
        float4 v0 = *(const float4*)src;
        float4 v1 = *(const float4*)(src + 4);
        u16x8 w;
        w[0] = f2bf(v0.x); w[1] = f2bf(v0.y); w[2] = f2bf(v0.z); w[3] = f2bf(v0.w);
        w[4] = f2bf(v1.x); w[5] = f2bf(v1.y); w[6] = f2bf(v1.z); w[7] = f2bf(v1.w);
        *(u16x8*)(Xbf + (size_t)m * 512 + (k8 ^ (m & 7)) * 8) = w;
    }
}

// ---------------------------------------------------------------------------
// Xg = Xbf @ Wih^T : M=32768, N=2048 (packed cols), K=512. 128x128 tile,
// BK=64, XCD-chunked block map, linear LDS staging, swizzled images.
// SINGLE-buffered LDS (32KB -> 5 blocks/CU) + register prefetch; 2 barriers.
// Epilogue: contiguous packed-col store.
// ---------------------------------------------------------------------------
__global__ __launch_bounds__(256) void xg_gemm(
    const unsigned short* __restrict__ Xbf,
    const unsigned short* __restrict__ Wihb,
    unsigned short* __restrict__ Xg) {
    __shared__ __align__(16) unsigned short As[8192];  // [128 rows][64 k] 16KB
    __shared__ __align__(16) unsigned short Bs[8192];
    const int tid = threadIdx.x;
    const int p = blockIdx.x;
    const int L = (p & 7) * 512 + (p >> 3);   // bijective XCD-chunked map
    const int bx = L >> 4, by = L & 15;
    const size_t m0 = (size_t)bx * 128;
    const int n0 = by * 128;
    const int wv = tid >> 6, lane = tid & 63;
    const int l15 = lane & 15, sel = lane >> 4;
    const int wm = wv >> 1, wn = wv & 1;

    // staging: thread tid <-> LDS byte tid*16 (+r*4096); linear, conflict-free
    const int srow = tid >> 3;        // + r*32
    const int sseg = tid & 7;         // *8 u16
    const unsigned short* asrc = Xbf + (m0 + srow) * 512 + sseg * 8;
    const unsigned short* bsrc = Wihb + (size_t)(n0 + srow) * 512 + sseg * 8;

    f32x4 acc[4][4];
#pragma unroll
    for (int i = 0; i < 4; ++i)
#pragma unroll
        for (int j = 0; j < 4; ++j) acc[i][j] = (f32x4){0.f, 0.f, 0.f, 0.f};

    u16x8 ar[4], br[4];
#pragma unroll
    for (int r = 0; r < 4; ++r) {
        ar[r] = *(const u16x8*)(asrc + (size_t)r * 32 * 512);
        br[r] = *(const u16x8*)(bsrc + (size_t)r * 32 * 512);
    }

#pragma unroll 1
    for (int it = 0; it < 8; ++it) {
        // write current tile (linear, conflict-free)
#pragma unroll
        for (int r = 0; r < 4; ++r) {
            *(u16x8*)((char*)As + r * 4096 + tid * 16) = ar[r];
            *(u16x8*)((char*)Bs + r * 4096 + tid * 16) = br[r];
        }
        // prefetch next tile into regs (completes during MFMA phase)
        if (it < 7) {
#pragma unroll
            for (int r = 0; r < 4; ++r) {
                ar[r] = *(const u16x8*)(asrc + (size_t)r * 32 * 512 + (it + 1) * 64);
                br[r] = *(const u16x8*)(bsrc + (size_t)r * 32 * 512 + (it + 1) * 64);
            }
        }
        __syncthreads();   // writes visible
#pragma unroll
        for (int ks = 0; ks < 2; ++ks) {
            bf16x8 a[4], b[4];
#pragma unroll
            for (int i = 0; i < 4; ++i) {
                const int arow = wm * 64 + i * 16 + l15;
                a[i] = *(const bf16x8*)(As + arow * 64 + (((ks * 4 + sel) ^ (arow & 7)) * 8));
                const int brow = wn * 64 + i * 16 + l15;
                b[i] = *(const bf16x8*)(Bs + brow * 64 + (((ks * 4 + sel) ^ (brow & 7)) * 8));
            }
#pragma unroll
            for (int i = 0; i < 4; ++i)
#pragma unroll
                for (int j = 0; j < 4; ++j)
                    acc[i][j] = __builtin_amdgcn_mfma_f32_16x16x32_bf16(a[i], b[j], acc[i][j], 0, 0, 0);
        }
        __syncthreads();   // reads done before next iter overwrites
    }
    // epilogue: contiguous packed-col store
#pragma unroll
    for (int i = 0; i < 4; ++i)
#pragma unroll
        for (int j = 0; j < 4; ++j) {
            const int col = n0 + wn * 64 + j * 16 + l15;
#pragma unroll
            for (int q = 0; q < 4; ++q) {
                const size_t m = m0 + wm * 64 + i * 16 + sel * 4 + q;
                Xg[m * 2048 + col] = f2bf(acc[i][j][q]);
            }
        }
}

// ---------------------------------------------------------------------------
// One LSTM step [R16 body]: gates = Xg[t] + h @ Whh^T; cell; h stored
// swizzled. Grid 256 (nt8 FAST x ut32), 512 thr = 8 waves (wm2 x wn4).
// BK=64 x 8 iters, double-buffered 32KB LDS (2 blocks/CU).
// nt = bid&7 => single owning XCD per h/c region.
// ---------------------------------------------------------------------------
__global__ __launch_bounds__(512) void lstm_step(
    const unsigned short* __restrict__ WhhImg,
    const unsigned short* __restrict__ Xg, const float* __restrict__ bsum,
    const unsigned short* __restrict__ h_in, unsigned short* __restrict__ h_out,
    float* __restrict__ c, int t) {
    __shared__ __align__(16) char smem[32768];
    float* dump = (float*)smem;          // [gate 4][row 64][cj 16]

    const int tid = threadIdx.x, bid = blockIdx.x;
    const int nt = bid & 7, ut = bid >> 3;
    const int n0 = nt * 64, u0 = ut * 16;
    const int wv = tid >> 6, lane = tid & 63;
    const int l15 = lane & 15, sel = lane >> 4;
    const int wm = wv >> 2, wn = wv & 3;         // wave tile: rows wm*32, gate wn
    const int srow = tid >> 3, sseg = tid & 7;
    const int wofs = srow * 128 + sseg * 16;     // == tid*16, linear

    const unsigned short* hsrc = h_in + (size_t)(n0 + srow) * 512 + sseg * 8;
    const unsigned short* wsrc = WhhImg + ut * 32768 + srow * 512 + sseg * 8;

    f32x4 acc0 = (f32x4){0.f, 0.f, 0.f, 0.f};
    f32x4 acc1 = (f32x4){0.f, 0.f, 0.f, 0.f};

    u16x8 hv = *(const u16x8*)hsrc;
    u16x8 wr = *(const u16x8*)wsrc;

#pragma unroll
    for (int it = 0; it < 8; ++it) {
        char* H = smem + (it & 1) * 8192;
        char* W = smem + 16384 + (it & 1) * 8192;
        *(u16x8*)(H + wofs) = hv;
        *(u16x8*)(W + wofs) = wr;
        if (it < 7) {
            hv = *(const u16x8*)(hsrc + (it + 1) * 64);
            wr = *(const u16x8*)(wsrc + (it + 1) * 64);
        }
        __syncthreads();
#pragma unroll
        for (int ks = 0; ks < 2; ++ks) {
            const int ar0 = wm * 32 + l15, ar1 = ar0 + 16;
            const int br = wn * 16 + l15;
            bf16x8 a0 = *(const bf16x8*)(H + ar0 * 128 + (((ks * 4 + sel) ^ (ar0 & 7)) * 16));
            bf16x8 a1 = *(const bf16x8*)(H + ar1 * 128 + (((ks * 4 + sel) ^ (ar1 & 7)) * 16));
            bf16x8 b  = *(const bf16x8*)(W + br * 128 + (((ks * 4 + sel) ^ (br & 7)) * 16));
            acc0 = __builtin_amdgcn_mfma_f32_16x16x32_bf16(a0, b, acc0, 0, 0, 0);
            acc1 = __builtin_amdgcn_mfma_f32_16x16x32_bf16(a1, b, acc1, 0, 0, 0);
        }
    }
    __syncthreads();   // all reads of LDS buffers done before dump overlays them

    // gate dump: wave (wm,wn) holds gate wn rows wm*32..+31
#pragma unroll
    for (int f = 0; f < 2; ++f)
#pragma unroll
        for (int q = 0; q < 4; ++q) {
            const int r = wm * 32 + f * 16 + sel * 4 + q;
            dump[wn * 1024 + r * 16 + l15] = (f ? acc1 : acc0)[q];
        }
    __syncthreads();

    // cell: 2 cells/thread; Xg packed u16x4 read
    const int crow = tid >> 4, cj = tid & 15;
    const float bI = bsum[u0 + cj];
    const float bF = bsum[512 + u0 + cj];
    const float bG = bsum[1024 + u0 + cj];
    const float bO = bsum[1536 + u0 + cj];
#pragma unroll
    for (int half = 0; half < 2; ++half) {
        const int r = crow + half * 32;
        const int n = n0 + r;
        const u16x4 xv = *(const u16x4*)(Xg + ((size_t)t * 512 + n) * 2048 + ut * 64 + cj * 4);
        const float gi = dump[0 * 1024 + r * 16 + cj] + bf2f(xv[0]) + bI;
        const float gf = dump[1 * 1024 + r * 16 + cj] + bf2f(xv[1]) + bF;
        const float gg = dump[2 * 1024 + r * 16 + cj] + bf2f(xv[2]) + bG;
        const float go = dump[3 * 1024 + r * 16 + cj] + bf2f(xv[3]) + bO;
        const size_t ci = (size_t)n * 512 + u0 + cj;
        const float I = sigmf(gi), F = sigmf(gf);
        const float G = tanh_fast(gg), O = sigmf(go);
        const float cn = F * c[ci] + I * G;
        c[ci] = cn;
        const int chunk = (ut * 2 + (cj >> 3)) ^ (n & 7);
        h_out[(size_t)n * 512 + chunk * 8 + (cj & 7)] = f2bf(O * tanh_fast(cn));
    }
}

// ---------------------------------------------------------------------------
// Head: pool (de-swizzle), fc1, fc2.
// ---------------------------------------------------------------------------
__global__ __launch_bounds__(256) void pool_kernel(
    const unsigned short* __restrict__ hfin, float* __restrict__ feat) {
    const int blk = blockIdx.x;
    const int b = blk >> 1, side = blk & 1;
    const int tid = threadIdx.x;
    for (int u = tid; u < Hn; u += 256) {
        float s = 0.0f, m = -1e30f;
#pragma unroll
        for (int ss = 0; ss < Sn; ++ss) {
            const int n = b * 32 + side * 16 + ss;
            const int chunk = (u >> 3) ^ (n & 7);
            float v = bf2f(hfin[(size_t)n * 512 + chunk * 8 + (u & 7)]);
            s += v;
            m = fmaxf(m, v);
        }
        feat[b * 2048 + side * 1024 + u] = s * (1.0f / 16.0f);
        feat[b * 2048 + side * 1024 + 512 + u] = m;
    }
}

__global__ __launch_bounds__(256) void fc1_kernel(
    const float* __restrict__ feat, const float* __restrict__ fc1w,
    const float* __restrict__ fc1b, float* __restrict__ z1) {
    __shared__ float fs[2048];
    __shared__ float red[256];
    const int b = blockIdx.x >> 4, oc = blockIdx.x & 15;
    const int tid = threadIdx.x;
    for (int k = tid; k < 2048; k += 256) fs[k] = feat[b * 2048 + k];
    __syncthreads();
    const int o = oc * 16 + (tid & 15);
    const int ks = (tid >> 4) * 128;
    const float4* w4 = (const float4*)(fc1w + (size_t)o * 2048 + ks);
    const float* fr = fs + ks;
    float p = 0.0f;
#pragma unroll 8
    for (int k = 0; k < 32; ++k) {
        float4 w = w4[k];
        p += fr[k * 4] * w.x + fr[k * 4 + 1] * w.y +
             fr[k * 4 + 2] * w.z + fr[k * 4 + 3] * w.w;
    }
    red[(tid & 15) * 16 + (tid >> 4)] = p;
    __syncthreads();
    if (tid < 16) {
        float z = fc1b[oc * 16 + tid];
#pragma unroll
        for (int j = 0; j < 16; ++j) z += red[tid * 16 + j];
        z1[b * 256 + oc * 16 + tid] = z;
    }
}

__global__ __launch_bounds__(256) void fc2_kernel(
    const float* __restrict__ z1, const float* __restrict__ fc2w,
    const float* __restrict__ fc2b, float* __restrict__ out) {
    __shared__ float sh[256];
    const int b = blockIdx.x, tid = threadIdx.x;
    sh[tid] = z1[b * 256 + tid] * fc2w[tid];
    __syncthreads();
    for (int s = 128; s > 0; s >>= 1) {
        if (tid < s) sh[tid] += sh[tid + s];
        __syncthreads();
    }
    if (tid == 0) out[b] = sigmf(sh[0] + fc2b[0]);
}

// ---------------------------------------------------------------------------
extern "C" void kernel_launch(void* const* d_in, const int* in_sizes, int n_in,
                              void* d_out, int out_size, void* d_ws, size_t ws_size,
                              hipStream_t stream) {
    const float* xf    = (const float*)d_in[0];
    const float* xa    = (const float*)d_in[1];
    const float* Wih_f = (const float*)d_in[2];
    const float* Whh_f = (const float*)d_in[3];
    const float* bih   = (const float*)d_in[4];
    const float* bhh   = (const float*)d_in[5];
    const float* fc1w  = (const float*)d_in[6];
    const float* fc1b  = (const float*)d_in[7];
    const float* fc2w  = (const float*)d_in[8];
    const float* fc2b  = (const float*)d_in[9];
    float* out = (float*)d_out;

    char* ws = (char*)d_ws;
    unsigned short* Wihb   = (unsigned short*)(ws + WS_WIHB);
    unsigned short* WhhImg = (unsigned short*)(ws + WS_WHH);
    float*          bsum   = (float*)(ws + WS_BSUM);
    unsigned short* hA     = (unsigned short*)(ws + WS_HA);
    unsigned short* hB     = (unsigned short*)(ws + WS_HB);
    float*          cbuf   = (float*)(ws + WS_C);
    float*          feat   = (float*)(ws + WS_FEAT);
    float*          z1     = (float*)(ws + WS_Z1);
    unsigned short* Xbf    = (unsigned short*)(ws + WS_XBF);
    unsigned short* Xg     = (unsigned short*)(ws + WS_XG);

    prep_all<<<dim3(PREP_BLOCKS), dim3(256), 0, stream>>>(
        Wih_f, Whh_f, bih, bhh, xf, xa, Wihb, WhhImg, bsum, hA, cbuf, Xbf);

    xg_gemm<<<dim3(4096), dim3(256), 0, stream>>>(Xbf, Wihb, Xg);

    for (int t = 0; t < Ln; ++t) {
        const unsigned short* hin = (t & 1) ? hB : hA;
        unsigned short* hout      = (t & 1) ? hA : hB;
        lstm_step<<<dim3(256), dim3(512), 0, stream>>>(
            WhhImg, Xg, bsum, hin, hout, cbuf, t);
    }
    // t=63 wrote hA
    pool_kernel<<<dim3(32), dim3(256), 0, stream>>>(hA, feat);
    fc1_kernel<<<dim3(256), dim3(256), 0, stream>>>(feat, fc1w, fc1b, z1);
    fc2_kernel<<<dim3(16), dim3(256), 0, stream>>>(z1, fc2w, fc2b, out);
}